// Round 1
// 357.350 us; speedup vs baseline: 1.0789x; 1.0789x over previous
//
#include <hip/hip_runtime.h>
#include <hip/hip_bf16.h>
#include <math.h>

#define BB 4096
#define TT 48
#define FF 64
#define HH 128
#define ROWS 16
#define NT 512
#define NBLK (BB / ROWS)   // 256

typedef __attribute__((ext_vector_type(8))) short short8;
typedef __attribute__((ext_vector_type(4))) float f32x4;

__device__ __forceinline__ float sigm(float x) { return 1.f / (1.f + __expf(-x)); }
__device__ __forceinline__ float tanh_f(float x) { return 2.f / (1.f + __expf(-2.f * x)) - 1.f; }

// ---- prep: pre-format ALL weights as bf16 MFMA B-fragments ----
// frag[...][lane][jj]: n = nt*16 + (lane&15), k = ks*32 + (lane>>4)*8 + jj
// Regions (element offsets):
//   [0,131072)        Wcat [512][256]  (W_ih | W_hh), 32 nt x 8 ks
//   [131072,139264)   Wdh  [128][64],   8 nt x 2 ks
//   [139264,147456)   Wh   [64][128],   4 nt x 4 ks
//   [147456,151552)   Wf   [64][64] diag-zeroed, 4 nt x 2 ks
//   [151552,159744)   Wc   [64][128],   4 nt x 4 ks
__global__ __launch_bounds__(256) void prep_kernel(
    const float* __restrict__ W_ih, const float* __restrict__ W_hh,
    const float* __restrict__ Wdh,  const float* __restrict__ Wh,
    const float* __restrict__ Wf,   const float* __restrict__ Wc,
    __hip_bfloat16* __restrict__ frags) {
    const int idx = blockIdx.x * 256 + threadIdx.x;  // < 159744
    float v;
    if (idx < 131072) {
        const int jj = idx & 7;
        const int lane = (idx >> 3) & 63;
        const int ks = (idx >> 9) & 7;
        const int tile = idx >> 12;
        const int n = tile * 16 + (lane & 15);
        const int k = ks * 32 + ((lane >> 4) << 3) + jj;
        v = (k < 128) ? W_ih[n * 128 + k] : W_hh[n * 128 + (k - 128)];
    } else {
        const int u = idx - 131072;
        const int jj = u & 7;
        const int lane = (u >> 3) & 63;
        const int lq = lane & 15, q8 = (lane >> 4) << 3;
        if (u < 8192) {                       // Wdh
            const int ks = (u >> 9) & 1, nt = u >> 10;
            const int n = nt * 16 + lq, k = ks * 32 + q8 + jj;
            v = Wdh[n * 64 + k];
        } else if (u < 16384) {               // Wh
            const int uu = u - 8192;
            const int ks = (uu >> 9) & 3, nt = uu >> 11;
            const int n = nt * 16 + lq, k = ks * 32 + q8 + jj;
            v = Wh[n * 128 + k];
        } else if (u < 20480) {               // Wf (diag zero)
            const int uu = u - 16384;
            const int ks = (uu >> 9) & 1, nt = uu >> 10;
            const int n = nt * 16 + lq, k = ks * 32 + q8 + jj;
            v = (k == n) ? 0.f : Wf[n * 64 + k];
        } else {                              // Wc
            const int uu = u - 20480;
            const int ks = (uu >> 9) & 3, nt = uu >> 11;
            const int n = nt * 16 + lq, k = ks * 32 + q8 + jj;
            v = Wc[n * 128 + k];
        }
    }
    frags[idx] = __float2bfloat16(v);
}

// ---- denom stage 1: partials[t*32+s] = sum over b-slice s (128 rows) of masks[b][t][:]
// masks are exactly 0.0/1.0 -> integer sums < 2^24 are exact in fp32 in any order.
__global__ __launch_bounds__(256) void denom1_kernel(const float* __restrict__ masks,
                                                     float* __restrict__ partials) {
    const int t = blockIdx.x >> 5;
    const int s = blockIdx.x & 31;
    const int tid = threadIdx.x;
    float acc = 0.f;
    #pragma unroll
    for (int k = 0; k < 8; ++k) {
        const int i = k * 256 + tid;            // 0..2047 float4s
        const int b = s * 128 + (i >> 4);
        const int f = (i & 15) << 2;
        const float4 v = *(const float4*)&masks[((size_t)b * TT + t) * FF + f];
        acc += v.x + v.y + v.z + v.w;
    }
    #pragma unroll
    for (int off = 32; off; off >>= 1) acc += __shfl_down(acc, off, 64);
    __shared__ float red[4];
    if ((tid & 63) == 0) red[tid >> 6] = acc;
    __syncthreads();
    if (tid == 0) partials[blockIdx.x] = red[0] + red[1] + red[2] + red[3];
}

__global__ __launch_bounds__(64) void denom2_kernel(const float* __restrict__ partials,
                                                    float* __restrict__ inv_denom) {
    const int t = threadIdx.x;
    if (t < TT) {
        float s = 0.f;
        #pragma unroll
        for (int i = 0; i < 32; ++i) s += partials[t * 32 + i];
        inv_denom[t] = 1.f / (s + 1e-5f);
    }
}

// ---- Main persistent kernel: block = 16 batch rows (one MFMA m-tile) ----
// 4 phases/step: A: gamma_h(w4-7) || alpha(w0-3, reg-resident); B: x_h; C: z_h+combine;
// D: gates+LSTM+stage(t+1). Next-step x/m/d prefetched into regs in A, consumed in D.
// Loss accumulated per-thread with precomputed inv_denom[t]; single reduce at end.
__global__ __launch_bounds__(NT, 2) void rits_kernel(
    const float* __restrict__ values, const float* __restrict__ masks,
    const float* __restrict__ deltas,
    const float* __restrict__ Wdx, const float* __restrict__ bdx,
    const float* __restrict__ bdh, const float* __restrict__ bh,
    const float* __restrict__ bf,  const float* __restrict__ bc,
    const float* __restrict__ b_ih, const float* __restrict__ b_hh,
    const float* __restrict__ Wo,  const float* __restrict__ bo,
    const __hip_bfloat16* __restrict__ frags,
    const float* __restrict__ inv_denom,
    float* __restrict__ ws_lossblk,
    float* __restrict__ out_imp, float* __restrict__ out_pred)
{
    __shared__ __hip_bfloat16 dbuf[ROWS][72];    // deltas (staged in D for t+1)
    __shared__ __hip_bfloat16 xcbuf[ROWS][72];   // x_c (B -> C)
    __shared__ __hip_bfloat16 hbufA[ROWS][136];  // h state (LSTM output, D -> A)
    __shared__ __hip_bfloat16 hbufB[ROWS][136];  // decayed h (A -> B,D)
    __shared__ __hip_bfloat16 gxm[ROWS][136];    // [gamma_x | m] (D -> A)
    __shared__ __hip_bfloat16 ccm[ROWS][136];    // [c_c | m]  (C/A -> D)
    __shared__ float x_lds[ROWS][65];            // x fp32 (D -> B)
    __shared__ float m_lds[ROWS][65];            // m fp32 (D -> B)
    __shared__ float redl[8];

    const int tid = threadIdx.x;
    const int bid = blockIdx.x;
    const int b0 = bid * ROWS;
    const int lane = tid & 63;
    const int wv = tid >> 6;        // wave 0..7
    const int quad = lane >> 4;
    const int lq = lane & 15;

    for (int i = tid; i < ROWS * 136; i += NT) ((unsigned short*)hbufA)[i] = 0;

    const float wdx_l = Wdx[lane * (FF + 1)];
    const float bdx_l = bdx[lane];

    const int j_ln = wv * 16 + lq;
    const float bI = b_ih[j_ln]       + b_hh[j_ln];
    const float bF = b_ih[128 + j_ln] + b_hh[128 + j_ln];
    const float bG = b_ih[256 + j_ln] + b_hh[256 + j_ln];
    const float bO = b_ih[384 + j_ln] + b_hh[384 + j_ln];

    const int f46 = (wv & 3) * 16 + lq;
    const float bh_f = bh[f46];
    const float bf_f = bf[f46];
    const float bc_f = bc[f46];

    // waves 4-7 own gamma_h n-tiles 2*(wv-4) and 2*(wv-4)+1
    const float bdh0 = bdh[(wv & 3) * 32 + lq];
    const float bdh1 = bdh[(wv & 3) * 32 + 16 + lq];

    const short8* f8 = (const short8*)frags;
    // short8-unit offsets: CAT 0, DH 16384, H 17408, F 18432, C 18944

    float c_reg[4];
    #pragma unroll
    for (int r = 0; r < 4; ++r) c_reg[r] = 0.f;
    float loss_acc = 0.f;

    // ---- prologue: load + stage t=0 ----
    float xn[2], mn[2], dn[2];
    #pragma unroll
    for (int q = 0; q < 2; ++q) {
        const int r = wv + 8 * q;
        const int off = ((b0 + r) * TT + 0) * FF + lane;
        xn[q] = values[off]; mn[q] = masks[off]; dn[q] = deltas[off];
    }
    #pragma unroll
    for (int q = 0; q < 2; ++q) {
        const int r = wv + 8 * q;
        x_lds[r][lane] = xn[q];
        m_lds[r][lane] = mn[q];
        dbuf[r][lane] = __float2bfloat16(dn[q]);
        const float gx = __expf(-fmaxf(fmaf(dn[q], wdx_l, bdx_l), 0.f));
        gxm[r][lane] = __float2bfloat16(gx);
        gxm[r][64 + lane] = __float2bfloat16(mn[q]);
    }
    __syncthreads();

    for (int t = 0; t < TT; ++t) {
        const float invd = inv_denom[t];

        // ---- Phase A: ccm m-half (from live regs); gamma_h (w4-7) || alpha (w0-3) ----
        #pragma unroll
        for (int q = 0; q < 2; ++q)
            ccm[wv + 8 * q][64 + lane] = __float2bfloat16(mn[q]);

        float al_r[4];
        if (wv < 4) {
            f32x4 acc = {0.f, 0.f, 0.f, 0.f};
            #pragma unroll
            for (int ks = 0; ks < 4; ++ks) {
                const short8 a = *(const short8*)&gxm[lq][ks * 32 + quad * 8];
                const short8 b = f8[18944 + ((wv * 4 + ks) << 6) + lane];
                acc = __builtin_amdgcn_mfma_f32_16x16x32_bf16(a, b, acc, 0, 0, 0);
            }
            #pragma unroll
            for (int r = 0; r < 4; ++r) al_r[r] = acc[r] + bc_f;   // alpha stays in regs
        } else {
            #pragma unroll
            for (int u = 0; u < 2; ++u) {
                const int tile = (wv - 4) * 2 + u;
                f32x4 acc = {0.f, 0.f, 0.f, 0.f};
                #pragma unroll
                for (int ks = 0; ks < 2; ++ks) {
                    const short8 a = *(const short8*)&dbuf[lq][ks * 32 + quad * 8];
                    const short8 b = f8[16384 + ((tile * 2 + ks) << 6) + lane];
                    acc = __builtin_amdgcn_mfma_f32_16x16x32_bf16(a, b, acc, 0, 0, 0);
                }
                const int col = tile * 16 + lq;
                const float bdh_c = (u == 0) ? bdh0 : bdh1;
                #pragma unroll
                for (int r = 0; r < 4; ++r) {
                    const int row = quad * 4 + r;
                    const float gh = __expf(-fmaxf(acc[r] + bdh_c, 0.f));
                    const float hd = __bfloat162float(hbufA[row][col]) * gh;
                    hbufB[row][col] = __float2bfloat16(hd);
                }
            }
        }
        // prefetch t+1 (clamped); consumed in D -> ~3 phases of latency cover
        {
            const int tn = (t < TT - 1) ? t + 1 : t;
            #pragma unroll
            for (int q = 0; q < 2; ++q) {
                const int r = wv + 8 * q;
                const int off = ((b0 + r) * TT + tn) * FF + lane;
                xn[q] = values[off]; mn[q] = masks[off]; dn[q] = deltas[off];
            }
        }
        __syncthreads();

        // ---- Phase B (w0-3): x_h = hd @ Wh.T ; loss1 ; x_c ----
        float xv_r[4], mv_r[4], xh_r[4];
        float stepsum = 0.f;
        if (wv < 4) {
            f32x4 acc = {0.f, 0.f, 0.f, 0.f};
            #pragma unroll
            for (int ks = 0; ks < 4; ++ks) {
                const short8 a = *(const short8*)&hbufB[lq][ks * 32 + quad * 8];
                const short8 b = f8[17408 + ((wv * 4 + ks) << 6) + lane];
                acc = __builtin_amdgcn_mfma_f32_16x16x32_bf16(a, b, acc, 0, 0, 0);
            }
            #pragma unroll
            for (int r = 0; r < 4; ++r) {
                const int row = quad * 4 + r;
                const float xh = acc[r] + bh_f;
                xh_r[r] = xh;
                const float xv = x_lds[row][f46], mv = m_lds[row][f46];
                xv_r[r] = xv; mv_r[r] = mv;
                stepsum += mv * fabsf(xv - xh);
                xcbuf[row][f46] = __float2bfloat16(fmaf(mv, xv, (1.f - mv) * xh));
            }
        }
        __syncthreads();

        // ---- Phase C (w0-3): z_h ; combine with reg-alpha ; loss2+3 ; c_c ----
        if (wv < 4) {
            f32x4 acc5 = {0.f, 0.f, 0.f, 0.f};
            #pragma unroll
            for (int ks = 0; ks < 2; ++ks) {
                const short8 a = *(const short8*)&xcbuf[lq][ks * 32 + quad * 8];
                const short8 b = f8[18432 + ((wv * 2 + ks) << 6) + lane];
                acc5 = __builtin_amdgcn_mfma_f32_16x16x32_bf16(a, b, acc5, 0, 0, 0);
            }
            #pragma unroll
            for (int r = 0; r < 4; ++r) {
                const int row = quad * 4 + r;
                const float zh = acc5[r] + bf_f;
                stepsum += mv_r[r] * fabsf(xv_r[r] - zh);
                const float alpha = al_r[r];
                const float ch = fmaf(alpha, zh, (1.f - alpha) * xh_r[r]);
                stepsum += mv_r[r] * fabsf(xv_r[r] - ch);
                const float cc = fmaf(mv_r[r], xv_r[r], (1.f - mv_r[r]) * ch);
                ccm[row][f46] = __float2bfloat16(cc);
                out_imp[((b0 + row) * TT + t) * FF + f46] = cc;
            }
        }
        loss_acc = fmaf(stepsum, invd, loss_acc);   // per-thread; reduced once at end
        __syncthreads();

        // ---- Phase D (all): gates = [c_c,m,hd] @ Wcat.T ; LSTM ; stage t+1 ----
        {
            f32x4 acc[4];
            #pragma unroll
            for (int g = 0; g < 4; ++g) acc[g] = (f32x4){0.f, 0.f, 0.f, 0.f};
            #pragma unroll
            for (int ks = 0; ks < 8; ++ks) {
                const short8 a = (ks < 4)
                    ? *(const short8*)&ccm[lq][ks * 32 + quad * 8]
                    : *(const short8*)&hbufB[lq][(ks - 4) * 32 + quad * 8];
                #pragma unroll
                for (int g = 0; g < 4; ++g) {
                    const short8 b = f8[(((g * 8 + wv) * 8 + ks) << 6) + lane];
                    acc[g] = __builtin_amdgcn_mfma_f32_16x16x32_bf16(a, b, acc[g], 0, 0, 0);
                }
            }
            // stage t+1 from prefetched regs (x_lds/m_lds read in B, dbuf/gxm in A: safe)
            #pragma unroll
            for (int q = 0; q < 2; ++q) {
                const int r = wv + 8 * q;
                x_lds[r][lane] = xn[q];
                m_lds[r][lane] = mn[q];
                dbuf[r][lane] = __float2bfloat16(dn[q]);
                const float gx = __expf(-fmaxf(fmaf(dn[q], wdx_l, bdx_l), 0.f));
                gxm[r][lane] = __float2bfloat16(gx);
                gxm[r][64 + lane] = __float2bfloat16(mn[q]);
            }
            #pragma unroll
            for (int r = 0; r < 4; ++r) {
                const float ig = sigm(acc[0][r] + bI);
                const float fg = sigm(acc[1][r] + bF);
                const float gg = tanh_f(acc[2][r] + bG);
                const float og = sigm(acc[3][r] + bO);
                c_reg[r] = fmaf(fg, c_reg[r], ig * gg);
                hbufA[quad * 4 + r][j_ln] = __float2bfloat16(og * tanh_f(c_reg[r]));
            }
        }
        __syncthreads();
    }

    // ---- predictions: h @ Wo.T + bo ----
    {
        const int r = tid >> 5, l = tid & 31;
        float s = 0.f;
        #pragma unroll
        for (int k = l; k < HH; k += 32) s += __bfloat162float(hbufA[r][k]) * Wo[k];
        #pragma unroll
        for (int off = 16; off; off >>= 1) s += __shfl_down(s, off, 32);
        if (l == 0) out_pred[b0 + r] = s + bo[0];
    }
    // ---- block loss partial (single reduction for whole kernel) ----
    #pragma unroll
    for (int off = 32; off; off >>= 1) loss_acc += __shfl_down(loss_acc, off, 64);
    if (lane == 0) redl[wv] = loss_acc;
    __syncthreads();
    if (tid == 0) {
        float s = 0.f;
        #pragma unroll
        for (int w = 0; w < 8; ++w) s += redl[w];
        ws_lossblk[bid] = s;
    }
}

// ---- final: loss = sum of 256 block partials ----
__global__ __launch_bounds__(256) void final_kernel(const float* __restrict__ ws_lossblk,
                                                    float* __restrict__ out_loss) {
    const int tid = threadIdx.x;
    float s = ws_lossblk[tid];
    #pragma unroll
    for (int off = 32; off; off >>= 1) s += __shfl_down(s, off, 64);
    __shared__ float red[4];
    if ((tid & 63) == 0) red[tid >> 6] = s;
    __syncthreads();
    if (tid == 0) out_loss[0] = red[0] + red[1] + red[2] + red[3];
}

extern "C" void kernel_launch(void* const* d_in, const int* in_sizes, int n_in,
                              void* d_out, int out_size, void* d_ws, size_t ws_size,
                              hipStream_t stream) {
    const float* values = (const float*)d_in[0];
    const float* masks  = (const float*)d_in[1];
    const float* deltas = (const float*)d_in[2];
    const float* Wdh  = (const float*)d_in[3];
    const float* bdh  = (const float*)d_in[4];
    const float* Wdx  = (const float*)d_in[5];
    const float* bdx  = (const float*)d_in[6];
    const float* Wh   = (const float*)d_in[7];
    const float* bh   = (const float*)d_in[8];
    const float* Wf   = (const float*)d_in[9];
    const float* bf   = (const float*)d_in[10];
    const float* Wc   = (const float*)d_in[11];
    const float* bc   = (const float*)d_in[12];
    const float* W_ih = (const float*)d_in[13];
    const float* W_hh = (const float*)d_in[14];
    const float* b_ih = (const float*)d_in[15];
    const float* b_hh = (const float*)d_in[16];
    const float* Wo   = (const float*)d_in[17];
    const float* bo   = (const float*)d_in[18];

    __hip_bfloat16* frags = (__hip_bfloat16*)d_ws;                 // 159744 bf16 = 319488 B
    float* inv_denom  = (float*)((char*)d_ws + 320 * 1024);        // [48] (pad to 64)
    float* partials   = inv_denom + 64;                            // [48*32]
    float* ws_lossblk = partials + 2048;                           // [256]

    float* out_loss = (float*)d_out;
    float* out_imp  = out_loss + 1;
    float* out_pred = out_imp + (size_t)BB * TT * FF;

    prep_kernel<<<624, 256, 0, stream>>>(W_ih, W_hh, Wdh, Wh, Wf, Wc, frags);
    denom1_kernel<<<TT * 32, 256, 0, stream>>>(masks, partials);
    denom2_kernel<<<1, 64, 0, stream>>>(partials, inv_denom);
    rits_kernel<<<NBLK, NT, 0, stream>>>(
        values, masks, deltas, Wdx, bdx, bdh, bh, bf, bc,
        b_ih, b_hh, Wo, bo, frags, inv_denom, ws_lossblk, out_imp, out_pred);
    final_kernel<<<1, 256, 0, stream>>>(ws_lossblk, out_loss);
}